// Round 4
// baseline (571.134 us; speedup 1.0000x reference)
//
#include <hip/hip_runtime.h>
#include <hip/hip_bf16.h>

// ---------------------------------------------------------------------------
// 2-layer bidirectional GRU, B=1024 T=512 H=31 IN=36 -> last step -> FC(62->7)
//
// Round 4: defeat load-sinking/remat. VGPR_Count stayed ~88 despite
// waves_per_eu(2,2): the scheduler sinks the loop-invariant weight loads into
// the 512-step loop (legal under __restrict__), re-reading ~100 floats/lane
// from L1 every step. Fix: pin each loaded weight with
// asm volatile("" : "+v"(w)) -- the value's producer becomes opaque volatile
// asm, which cannot be sunk or rematerialized, forcing true VGPR residency.
//  * l0: waves_per_eu(2,2) (VGPR budget 256, need ~200).
//  * l1: waves_per_eu(1,1) (budget 512, need ~250).
//  * structure unchanged: 1 wave per (batch,dir); 64 lanes = 32 units x 2
//    k-halves combined via __shfl_xor(.,32); h in wave-local LDS (no
//    barriers inside the 512-step loop); double-buffered x prefetch.
//  * L1 backward = ONE GRU step at t=T-1 (only last timestep is consumed).
// ---------------------------------------------------------------------------

#define NB 1024
#define NT 512
#define NH 31
#define NG 93
#define NC 7

__device__ __forceinline__ float sig_(float x) { return 1.f / (1.f + __expf(-x)); }
__device__ __forceinline__ float th_(float x)  { float e = __expf(2.f * x); return (e - 1.f) / (e + 1.f); }

__device__ __forceinline__ float tf_(float v) { return v; }
__device__ __forceinline__ float tf_(__hip_bfloat16 v) { return __bfloat162float(v); }

__device__ __forceinline__ void ldpair(const float* p, float& a, float& b) {
    float2 v = *(const float2*)p; a = v.x; b = v.y;
}
__device__ __forceinline__ void ldpair(const __hip_bfloat16* p, float& a, float& b) {
    ushort2 u = *(const ushort2*)p;
    a = __uint_as_float((unsigned)u.x << 16);
    b = __uint_as_float((unsigned)u.y << 16);
}
__device__ __forceinline__ void stoy(float* p, float v) { *p = v; }
__device__ __forceinline__ void stoy(__hip_bfloat16* p, float v) { *p = __float2bfloat16(v); }

// Pin a register-resident value: producer becomes opaque volatile asm ->
// cannot be sunk into the loop or rematerialized from its load.
#define PIN(v_) asm volatile("" : "+v"(v_))

#define LOADX(arr, ptr)                                                   \
    _Pragma("unroll") for (int k_ = 0; k_ < KH; k_ += 2)                  \
        ldpair((ptr) + k_, arr[k_], arr[k_ + 1])

#define GRU_STEP(XV)                                                      \
    do {                                                                  \
        const float4 g0 = *(const float4*)&hbuf[w][hlo + 0];              \
        const float4 g1 = *(const float4*)&hbuf[w][hlo + 4];              \
        const float4 g2 = *(const float4*)&hbuf[w][hlo + 8];              \
        const float4 g3 = *(const float4*)&hbuf[w][hlo + 12];             \
        float hv[16];                                                     \
        hv[0]=g0.x;  hv[1]=g0.y;  hv[2]=g0.z;  hv[3]=g0.w;                \
        hv[4]=g1.x;  hv[5]=g1.y;  hv[6]=g1.z;  hv[7]=g1.w;                \
        hv[8]=g2.x;  hv[9]=g2.y;  hv[10]=g2.z; hv[11]=g2.w;               \
        hv[12]=g3.x; hv[13]=g3.y; hv[14]=g3.z; hv[15]=g3.w;               \
        float ar = b_r, az = b_z, an = b_xn, ah = b_hn;                   \
        _Pragma("unroll") for (int k_ = 0; k_ < KH; ++k_) {               \
            ar = fmaf(Wxr[k_], XV[k_], ar);                               \
            az = fmaf(Wxz[k_], XV[k_], az);                               \
            an = fmaf(Wxn[k_], XV[k_], an);                               \
        }                                                                 \
        _Pragma("unroll") for (int k_ = 0; k_ < 16; ++k_) {               \
            ar = fmaf(Whr[k_], hv[k_], ar);                               \
            az = fmaf(Whz[k_], hv[k_], az);                               \
            ah = fmaf(Whn[k_], hv[k_], ah);                               \
        }                                                                 \
        ar += __shfl_xor(ar, 32, 64);                                     \
        az += __shfl_xor(az, 32, 64);                                     \
        an += __shfl_xor(an, 32, 64);                                     \
        ah += __shfl_xor(ah, 32, 64);                                     \
        const float r_ = sig_(ar);                                        \
        const float z_ = sig_(az);                                        \
        const float n_ = th_(an + r_ * ah);                               \
        h_prev = n_ + z_ * (h_prev - n_);                                 \
        if (half == 0 && j < NH) {                                        \
            hbuf[w][j] = h_prev;                                          \
            if (WRITE_Y) stoy(yp, h_prev);                                \
        }                                                                 \
    } while (0)

// XT: input elem type, YT: y0 store type. KH: per-half k-count (compile-time).
// half0 covers k in [0, DIN-KH) plus zero-pad to KH; half1 covers [DIN-KH, DIN).
template<typename XT, typename YT, int DIN, int KH, bool WRITE_Y, bool WRITE_HF>
__device__ __forceinline__ void gru_scan_body(
    const XT* __restrict__ xin,
    const float* __restrict__ Wih, const float* __restrict__ Whh,
    const float* __restrict__ bih, const float* __restrict__ bhh,
    int dir, YT* __restrict__ y, float* __restrict__ hf)
{
    static_assert((KH & 1) == 0, "even KH");
    const int tid  = threadIdx.x;
    const int w    = tid >> 6;
    const int lane = tid & 63;
    const int half = lane >> 5;
    const int j    = lane & 31;
    const int jj   = j < NH ? j : NH - 1;
    const int b    = blockIdx.x * 4 + w;

    __shared__ __align__(16) float hbuf[4][32];
    if (lane < 32) hbuf[w][lane] = 0.f;
    __syncthreads();

    const int klo = half ? (DIN - KH) : 0;

    // Wih row-slices in VGPRs. half0 valid for k < DIN-KH (l0: all 18; l1: 30).
    float Wxr[KH], Wxz[KH], Wxn[KH];
#pragma unroll
    for (int k = 0; k < KH; ++k) {
        const bool v = half ? true : (k < DIN - KH);
        Wxr[k] = v ? Wih[(0 * NH + jj) * DIN + klo + k] : 0.f;
        Wxz[k] = v ? Wih[(1 * NH + jj) * DIN + klo + k] : 0.f;
        Wxn[k] = v ? Wih[(2 * NH + jj) * DIN + klo + k] : 0.f;
        PIN(Wxr[k]); PIN(Wxz[k]); PIN(Wxn[k]);
    }
    const int hlo = half * 16;
    float Whr[16], Whz[16], Whn[16];
#pragma unroll
    for (int k = 0; k < 16; ++k) {
        const bool v = (hlo + k) < NH;
        Whr[k] = v ? Whh[(0 * NH + jj) * NH + hlo + k] : 0.f;
        Whz[k] = v ? Whh[(1 * NH + jj) * NH + hlo + k] : 0.f;
        Whn[k] = v ? Whh[(2 * NH + jj) * NH + hlo + k] : 0.f;
        PIN(Whr[k]); PIN(Whz[k]); PIN(Whn[k]);
    }
    // biases only on half0 (summed once; shfl_xor sum delivers to both halves)
    float b_r = 0.f, b_z = 0.f, b_xn = 0.f, b_hn = 0.f;
    if (half == 0) {
        b_r  = bih[jj] + bhh[jj];
        b_z  = bih[NH + jj] + bhh[NH + jj];
        b_xn = bih[2 * NH + jj];
        b_hn = bhh[2 * NH + jj];
    }
    PIN(b_r); PIN(b_z); PIN(b_xn); PIN(b_hn);

    const XT* xrow = xin + (size_t)b * NT * DIN + klo
                   + (dir ? (size_t)(NT - 1) * DIN : 0);
    const ptrdiff_t xstep = dir ? -DIN : DIN;
    YT* yp = nullptr;
    ptrdiff_t ystep = 0;
    if (WRITE_Y) {
        yp = y + (size_t)b * NT * 62 + dir * NH + j
           + (dir ? (size_t)(NT - 1) * 62 : 0);
        ystep = dir ? -62 : 62;
    }

    float h_prev = 0.f;
    float xa[KH], xb[KH];
    LOADX(xa, xrow);
    const XT* xpre = xrow + xstep;

    for (int s = 0; s < NT; s += 2) {
        LOADX(xb, xpre);                       // row s+1
        if (s + 2 < NT) xpre += xstep;         // -> row s+2 (clamped)
        GRU_STEP(xa);                          // step s
        if (WRITE_Y) yp += ystep;
        LOADX(xa, xpre);                       // row s+2 (or clamp re-read)
        if (s + 3 < NT) xpre += xstep;         // -> row s+3
        GRU_STEP(xb);                          // step s+1
        if (WRITE_Y) yp += ystep;
    }
    if (WRITE_HF && half == 0 && j < NH) hf[b * NH + j] = h_prev;
}

template<typename YT>
__global__ void __launch_bounds__(256)
__attribute__((amdgpu_waves_per_eu(2, 2)))
gru_scan_l0(
    const float* __restrict__ x,
    const float* __restrict__ Wf, const float* __restrict__ Uf,
    const float* __restrict__ bf, const float* __restrict__ cf,
    const float* __restrict__ Wb, const float* __restrict__ Ub,
    const float* __restrict__ bb, const float* __restrict__ cb,
    YT* __restrict__ y)
{
    const int d = blockIdx.y;
    gru_scan_body<float, YT, 36, 18, true, false>(
        x, d ? Wb : Wf, d ? Ub : Uf, d ? bb : bf, d ? cb : cf, d, y, nullptr);
}

template<typename YT>
__global__ void __launch_bounds__(256)
__attribute__((amdgpu_waves_per_eu(1, 1)))
gru_scan_l1(
    const YT* __restrict__ y0,
    const float* __restrict__ W, const float* __restrict__ U,
    const float* __restrict__ bi, const float* __restrict__ bh,
    float* __restrict__ hf)
{
    gru_scan_body<YT, YT, 62, 32, false, true>(y0, W, U, bi, bh, 0, (YT*)nullptr, hf);
}

// L1 backward single step at t=T-1 (h0=0) + FC. One wave per batch.
template<typename YT>
__global__ void __launch_bounds__(64, 4) gru_final(
    const YT* __restrict__ y0, const float* __restrict__ hf,
    const float* __restrict__ Wih1b, const float* __restrict__ bih1b,
    const float* __restrict__ bhh1b,
    const float* __restrict__ fcw, const float* __restrict__ fcb,
    float* __restrict__ out)
{
    const int b = blockIdx.x;
    const int lane = threadIdx.x;
    __shared__ float row[62];
    __shared__ float xg[NG];
    __shared__ float last[62];
    const YT* yl = y0 + ((size_t)b * NT + (NT - 1)) * 62;
    if (lane < 62) row[lane] = tf_(yl[lane]);
    __syncthreads();
    for (int g = lane; g < NG; g += 64) {
        float a = bih1b[g];
        const float* wr = Wih1b + g * 62;
#pragma unroll
        for (int k = 0; k < 62; ++k) a = fmaf(wr[k], row[k], a);
        xg[g] = a;
    }
    if (lane < NH) last[lane] = hf[b * NH + lane];
    __syncthreads();
    if (lane < NH) {
        const float r = sig_(xg[lane] + bhh1b[lane]);
        const float z = sig_(xg[NH + lane] + bhh1b[NH + lane]);
        const float n = th_(xg[2 * NH + lane] + r * bhh1b[2 * NH + lane]);
        last[NH + lane] = (1.f - z) * n;   // + z*h0, h0 = 0
    }
    __syncthreads();
    if (lane < NC) {
        float a = fcb[lane];
        const float* wr = fcw + lane * 62;
#pragma unroll
        for (int k = 0; k < 62; ++k) a = fmaf(wr[k], last[k], a);
        out[b * NC + lane] = a;
    }
}

extern "C" void kernel_launch(void* const* d_in, const int* in_sizes, int n_in,
                              void* d_out, int out_size, void* d_ws, size_t ws_size,
                              hipStream_t stream)
{
    const float* x     = (const float*)d_in[0];
    const float* Wih0f = (const float*)d_in[1];
    const float* Whh0f = (const float*)d_in[2];
    const float* bih0f = (const float*)d_in[3];
    const float* bhh0f = (const float*)d_in[4];
    const float* Wih0b = (const float*)d_in[5];
    const float* Whh0b = (const float*)d_in[6];
    const float* bih0b = (const float*)d_in[7];
    const float* bhh0b = (const float*)d_in[8];
    const float* Wih1f = (const float*)d_in[9];
    const float* Whh1f = (const float*)d_in[10];
    const float* bih1f = (const float*)d_in[11];
    const float* bhh1f = (const float*)d_in[12];
    const float* Wih1b = (const float*)d_in[13];
    const float* Whh1b = (const float*)d_in[14];  // unused: single step from h0=0
    const float* bih1b = (const float*)d_in[15];
    const float* bhh1b = (const float*)d_in[16];
    const float* fcw   = (const float*)d_in[17];
    const float* fcb   = (const float*)d_in[18];
    float* out = (float*)d_out;
    (void)Whh1b; (void)in_sizes; (void)n_in; (void)out_size;

    const size_t y0_elems  = (size_t)NB * NT * 62;
    const size_t hf_bytes  = (size_t)NB * NH * 4;
    const size_t need_f32  = y0_elems * 4 + 256 + hf_bytes;
    const size_t need_bf16 = y0_elems * 2 + 256 + hf_bytes;

    const dim3 blk(256);
    if (ws_size >= need_f32) {
        float* y0 = (float*)d_ws;
        float* hf = (float*)((char*)d_ws + ((y0_elems * 4 + 255) & ~(size_t)255));
        gru_scan_l0<float><<<dim3(NB / 4, 2), blk, 0, stream>>>(
            x, Wih0f, Whh0f, bih0f, bhh0f, Wih0b, Whh0b, bih0b, bhh0b, y0);
        gru_scan_l1<float><<<dim3(NB / 4, 1), blk, 0, stream>>>(
            y0, Wih1f, Whh1f, bih1f, bhh1f, hf);
        gru_final<float><<<dim3(NB), dim3(64), 0, stream>>>(
            y0, hf, Wih1b, bih1b, bhh1b, fcw, fcb, out);
    } else if (ws_size >= need_bf16) {
        __hip_bfloat16* y0 = (__hip_bfloat16*)d_ws;
        float* hf = (float*)((char*)d_ws + ((y0_elems * 2 + 255) & ~(size_t)255));
        gru_scan_l0<__hip_bfloat16><<<dim3(NB / 4, 2), blk, 0, stream>>>(
            x, Wih0f, Whh0f, bih0f, bhh0f, Wih0b, Whh0b, bih0b, bhh0b, y0);
        gru_scan_l1<__hip_bfloat16><<<dim3(NB / 4, 1), blk, 0, stream>>>(
            y0, Wih1f, Whh1f, bih1f, bhh1f, hf);
        gru_final<__hip_bfloat16><<<dim3(NB), dim3(64), 0, stream>>>(
            y0, hf, Wih1b, bih1b, bhh1b, fcw, fcb, out);
    }
}

// Round 5
// 570.368 us; speedup vs baseline: 1.0013x; 1.0013x over previous
//
#include <hip/hip_runtime.h>
#include <hip/hip_bf16.h>

// ---------------------------------------------------------------------------
// 2-layer bidirectional GRU, B=1024 T=512 H=31 IN=36 -> last step -> FC(62->7)
//
// Round 5: stop fighting the register allocator (3 rounds, VGPR stuck at 88,
// ~3.3x VALU bloat/step from per-step weight reloads). Restructure so the
// scan doesn't need ~150 live floats/lane:
//   * xg = Wih.x + bih precomputed by a throughput GEMM kernel (gru_xg36 /
//     gru_xg62): x row in VGPRs, W via uniform loads, f32, 96-padded rows.
//   * lean scan needs only Whh (48 floats) + 12 xg prefetch regs -> ~100
//     live, allocatable. 4-deep xg prefetch (a..d sets) covers HBM latency.
//   * l1-forward xg reuses the xg buffer (scan l0 consumed it already).
//   * Tier A needs ws >= ~533 MB; round-4 fused path kept as fallback
//     (dispatch names reveal which tier ran).
//  * L1 backward = ONE GRU step at t=T-1 (only last timestep is consumed).
// ---------------------------------------------------------------------------

#define NB 1024
#define NT 512
#define NH 31
#define NG 93
#define NC 7
#define BT (NB * NT)
#define XGP 96   // padded xg row stride (floats)

__device__ __forceinline__ float sig_(float x) { return 1.f / (1.f + __expf(-x)); }
__device__ __forceinline__ float th_(float x)  { float e = __expf(2.f * x); return (e - 1.f) / (e + 1.f); }

__device__ __forceinline__ float tf_(float v) { return v; }
__device__ __forceinline__ float tf_(__hip_bfloat16 v) { return __bfloat162float(v); }

__device__ __forceinline__ void ldpair(const float* p, float& a, float& b) {
    float2 v = *(const float2*)p; a = v.x; b = v.y;
}
__device__ __forceinline__ void ldpair(const __hip_bfloat16* p, float& a, float& b) {
    ushort2 u = *(const ushort2*)p;
    a = __uint_as_float((unsigned)u.x << 16);
    b = __uint_as_float((unsigned)u.y << 16);
}
__device__ __forceinline__ void stoy(float* p, float v) { *p = v; }
__device__ __forceinline__ void stoy(__hip_bfloat16* p, float v) { *p = __float2bfloat16(v); }

// ============================ Tier A kernels ================================

// xg GEMM: out[d][row][g] = sum_k W_d[g][k] * xin[row][k] + bi_d[g]
// row = b*T + t. One thread per row; W rows are wave-uniform loads.
template<int DIN, int NDIR>
__global__ void __launch_bounds__(256)
__attribute__((amdgpu_waves_per_eu(1, 4)))
gru_xg(const float* __restrict__ xin,
       const float* __restrict__ W0, const float* __restrict__ bi0,
       const float* __restrict__ W1, const float* __restrict__ bi1,
       float* __restrict__ xg)
{
    __shared__ float tile[256 * DIN];
    const int tid = threadIdx.x;
    const size_t blk0 = (size_t)blockIdx.x * 256;

    // stage 256 rows, coalesced float2
    {
        const float2* gsrc = (const float2*)(xin + blk0 * DIN);
        float2* lds2 = (float2*)tile;
#pragma unroll
        for (int i = 0; i < DIN / 2; ++i)
            lds2[tid + i * 256] = gsrc[tid + i * 256];
    }
    __syncthreads();

    float xr[DIN];
#pragma unroll
    for (int k = 0; k < DIN; k += 2) {
        float2 v = *(const float2*)&tile[tid * DIN + k];
        xr[k] = v.x; xr[k + 1] = v.y;
    }
    const size_t row = blk0 + tid;

#pragma unroll
    for (int d = 0; d < NDIR; ++d) {
        const float* __restrict__ W  = d ? W1 : W0;
        const float* __restrict__ bi = d ? bi1 : bi0;
        float* outp = xg + (d * (size_t)BT + row) * XGP;
        for (int g = 0; g < NG - 1; g += 4) {
            float a0 = bi[g], a1 = bi[g + 1], a2 = bi[g + 2], a3 = bi[g + 3];
#pragma unroll
            for (int k = 0; k < DIN; ++k) {
                const float xv = xr[k];
                a0 = fmaf(W[(g + 0) * DIN + k], xv, a0);
                a1 = fmaf(W[(g + 1) * DIN + k], xv, a1);
                a2 = fmaf(W[(g + 2) * DIN + k], xv, a2);
                a3 = fmaf(W[(g + 3) * DIN + k], xv, a3);
            }
            float4 o; o.x = a0; o.y = a1; o.z = a2; o.w = a3;
            *(float4*)(outp + g) = o;
        }
        {   // g = 92
            float a = bi[NG - 1];
#pragma unroll
            for (int k = 0; k < DIN; ++k)
                a = fmaf(W[(NG - 1) * DIN + k], xr[k], a);
            outp[NG - 1] = a;
        }
    }
}

// Lean scan: per wave = one (batch, dir). Lanes = 32 units x 2 h-halves.
// xg rows streamed with 4-deep prefetch; h in wave-local LDS (no barriers).
#define LDG3(R_, Z_, N_, P_)                                              \
    do { R_ = (P_)[jj]; Z_ = (P_)[NH + jj]; N_ = (P_)[2 * NH + jj]; } while (0)

#define ADVX()                                                            \
    do { if (++tl < NT) xq += xqs; } while (0)

#define LSTEP(XR_, XZ_, XN_)                                              \
    do {                                                                  \
        const float4 q0 = *(const float4*)&hbuf[w][hlo + 0];              \
        const float4 q1 = *(const float4*)&hbuf[w][hlo + 4];              \
        const float4 q2 = *(const float4*)&hbuf[w][hlo + 8];              \
        const float4 q3 = *(const float4*)&hbuf[w][hlo + 12];             \
        float hv[16];                                                     \
        hv[0]=q0.x;  hv[1]=q0.y;  hv[2]=q0.z;  hv[3]=q0.w;                \
        hv[4]=q1.x;  hv[5]=q1.y;  hv[6]=q1.z;  hv[7]=q1.w;                \
        hv[8]=q2.x;  hv[9]=q2.y;  hv[10]=q2.z; hv[11]=q2.w;               \
        hv[12]=q3.x; hv[13]=q3.y; hv[14]=q3.z; hv[15]=q3.w;               \
        float ar = fmaf(hm, XR_, b_r);                                    \
        float az = fmaf(hm, XZ_, b_z);                                    \
        float an = hm * (XN_);                                            \
        float ah = b_hn;                                                  \
        _Pragma("unroll") for (int k_ = 0; k_ < 16; ++k_) {               \
            ar = fmaf(Whr[k_], hv[k_], ar);                               \
            az = fmaf(Whz[k_], hv[k_], az);                               \
            ah = fmaf(Whn[k_], hv[k_], ah);                               \
        }                                                                 \
        ar += __shfl_xor(ar, 32, 64);                                     \
        az += __shfl_xor(az, 32, 64);                                     \
        an += __shfl_xor(an, 32, 64);                                     \
        ah += __shfl_xor(ah, 32, 64);                                     \
        const float r_ = sig_(ar);                                        \
        const float z_ = sig_(az);                                        \
        const float n_ = th_(an + r_ * ah);                               \
        h_prev = n_ + z_ * (h_prev - n_);                                 \
        if (half == 0 && j < NH) {                                        \
            hbuf[w][j] = h_prev;                                          \
            if (WRITE_Y) *yp = h_prev;                                    \
        }                                                                 \
        if (WRITE_Y) yp += ystep;                                         \
    } while (0)

template<bool WRITE_Y, bool WRITE_HF>
__device__ __forceinline__ void gru_scan_lean_body(
    const float* __restrict__ xgd,   // xg base for this dir: [BT][XGP]
    const float* __restrict__ Whh, const float* __restrict__ bhh,
    int dir, float* __restrict__ y, float* __restrict__ hf)
{
    const int tid  = threadIdx.x;
    const int w    = tid >> 6;
    const int lane = tid & 63;
    const int half = lane >> 5;
    const int j    = lane & 31;
    const int jj   = j < NH ? j : NH - 1;
    const int b    = blockIdx.x * 4 + w;

    __shared__ __align__(16) float hbuf[4][32];
    if (lane < 32) hbuf[w][lane] = 0.f;
    __syncthreads();

    const int hlo = half * 16;
    float Whr[16], Whz[16], Whn[16];
#pragma unroll
    for (int k = 0; k < 16; ++k) {
        const bool v = (hlo + k) < NH;
        Whr[k] = v ? Whh[(0 * NH + jj) * NH + hlo + k] : 0.f;
        Whz[k] = v ? Whh[(1 * NH + jj) * NH + hlo + k] : 0.f;
        Whn[k] = v ? Whh[(2 * NH + jj) * NH + hlo + k] : 0.f;
    }
    float b_r = 0.f, b_z = 0.f, b_hn = 0.f;
    if (half == 0) {
        b_r  = bhh[jj];
        b_z  = bhh[NH + jj];
        b_hn = bhh[2 * NH + jj];
    }
    const float hm = (half == 0) ? 1.f : 0.f;

    const float* xq = xgd + ((size_t)b * NT + (dir ? NT - 1 : 0)) * XGP;
    const ptrdiff_t xqs = dir ? -XGP : XGP;
    float* yp = nullptr;
    ptrdiff_t ystep = 0;
    if (WRITE_Y) {
        yp = y + (size_t)b * NT * 62 + dir * NH + j
           + (dir ? (size_t)(NT - 1) * 62 : 0);
        ystep = dir ? -62 : 62;
    }

    float h_prev = 0.f;
    int tl = 0;
    float ra, za, na, rb, zb, nb, rc, zc, nc, rd, zd, nd;
    LDG3(ra, za, na, xq); ADVX();
    LDG3(rb, zb, nb, xq); ADVX();
    LDG3(rc, zc, nc, xq); ADVX();

    for (int it = 0; it < NT / 4; ++it) {
        LDG3(rd, zd, nd, xq); ADVX();
        LSTEP(ra, za, na);
        LDG3(ra, za, na, xq); ADVX();
        LSTEP(rb, zb, nb);
        LDG3(rb, zb, nb, xq); ADVX();
        LSTEP(rc, zc, nc);
        LDG3(rc, zc, nc, xq); ADVX();
        LSTEP(rd, zd, nd);
    }
    if (WRITE_HF && half == 0 && j < NH) hf[b * NH + j] = h_prev;
}

__global__ void __launch_bounds__(256)
__attribute__((amdgpu_waves_per_eu(2, 2)))
gru_scan_lean_l0(const float* __restrict__ xg,
                 const float* __restrict__ Uf, const float* __restrict__ cf,
                 const float* __restrict__ Ub, const float* __restrict__ cb,
                 float* __restrict__ y)
{
    const int d = blockIdx.y;
    gru_scan_lean_body<true, false>(xg + (size_t)d * BT * XGP,
                                    d ? Ub : Uf, d ? cb : cf, d, y, nullptr);
}

__global__ void __launch_bounds__(256)
__attribute__((amdgpu_waves_per_eu(1, 1)))
gru_scan_lean_l1(const float* __restrict__ xg,
                 const float* __restrict__ U, const float* __restrict__ c,
                 float* __restrict__ hf)
{
    gru_scan_lean_body<false, true>(xg, U, c, 0, nullptr, hf);
}

// L1 backward single step at t=T-1 (h0=0) + FC. One wave per batch.
__global__ void __launch_bounds__(64, 4) gru_final(
    const float* __restrict__ y0, const float* __restrict__ hf,
    const float* __restrict__ Wih1b, const float* __restrict__ bih1b,
    const float* __restrict__ bhh1b,
    const float* __restrict__ fcw, const float* __restrict__ fcb,
    float* __restrict__ out)
{
    const int b = blockIdx.x;
    const int lane = threadIdx.x;
    __shared__ float row[62];
    __shared__ float xg[NG];
    __shared__ float last[62];
    const float* yl = y0 + ((size_t)b * NT + (NT - 1)) * 62;
    if (lane < 62) row[lane] = yl[lane];
    __syncthreads();
    for (int g = lane; g < NG; g += 64) {
        float a = bih1b[g];
        const float* wr = Wih1b + g * 62;
#pragma unroll
        for (int k = 0; k < 62; ++k) a = fmaf(wr[k], row[k], a);
        xg[g] = a;
    }
    if (lane < NH) last[lane] = hf[b * NH + lane];
    __syncthreads();
    if (lane < NH) {
        const float r = sig_(xg[lane] + bhh1b[lane]);
        const float z = sig_(xg[NH + lane] + bhh1b[NH + lane]);
        const float n = th_(xg[2 * NH + lane] + r * bhh1b[2 * NH + lane]);
        last[NH + lane] = (1.f - z) * n;   // + z*h0, h0 = 0
    }
    __syncthreads();
    if (lane < NC) {
        float a = fcb[lane];
        const float* wr = fcw + lane * 62;
#pragma unroll
        for (int k = 0; k < 62; ++k) a = fmaf(wr[k], last[k], a);
        out[b * NC + lane] = a;
    }
}

// ====================== Fallback (round-4 fused) ============================

#define PIN(v_) asm volatile("" : "+v"(v_))

#define LOADX(arr, ptr)                                                   \
    _Pragma("unroll") for (int k_ = 0; k_ < KH; k_ += 2)                  \
        ldpair((ptr) + k_, arr[k_], arr[k_ + 1])

#define GRU_STEP(XV)                                                      \
    do {                                                                  \
        const float4 g0 = *(const float4*)&hbuf[w][hlo + 0];              \
        const float4 g1 = *(const float4*)&hbuf[w][hlo + 4];              \
        const float4 g2 = *(const float4*)&hbuf[w][hlo + 8];              \
        const float4 g3 = *(const float4*)&hbuf[w][hlo + 12];             \
        float hv[16];                                                     \
        hv[0]=g0.x;  hv[1]=g0.y;  hv[2]=g0.z;  hv[3]=g0.w;                \
        hv[4]=g1.x;  hv[5]=g1.y;  hv[6]=g1.z;  hv[7]=g1.w;                \
        hv[8]=g2.x;  hv[9]=g2.y;  hv[10]=g2.z; hv[11]=g2.w;               \
        hv[12]=g3.x; hv[13]=g3.y; hv[14]=g3.z; hv[15]=g3.w;               \
        float ar = b_r, az = b_z, an = b_xn, ah = b_hn;                   \
        _Pragma("unroll") for (int k_ = 0; k_ < KH; ++k_) {               \
            ar = fmaf(Wxr[k_], XV[k_], ar);                               \
            az = fmaf(Wxz[k_], XV[k_], az);                               \
            an = fmaf(Wxn[k_], XV[k_], an);                               \
        }                                                                 \
        _Pragma("unroll") for (int k_ = 0; k_ < 16; ++k_) {               \
            ar = fmaf(Whr[k_], hv[k_], ar);                               \
            az = fmaf(Whz[k_], hv[k_], az);                               \
            ah = fmaf(Whn[k_], hv[k_], ah);                               \
        }                                                                 \
        ar += __shfl_xor(ar, 32, 64);                                     \
        az += __shfl_xor(az, 32, 64);                                     \
        an += __shfl_xor(an, 32, 64);                                     \
        ah += __shfl_xor(ah, 32, 64);                                     \
        const float r_ = sig_(ar);                                        \
        const float z_ = sig_(az);                                        \
        const float n_ = th_(an + r_ * ah);                               \
        h_prev = n_ + z_ * (h_prev - n_);                                 \
        if (half == 0 && j < NH) {                                        \
            hbuf[w][j] = h_prev;                                          \
            if (WRITE_Y) stoy(yp, h_prev);                                \
        }                                                                 \
    } while (0)

template<typename XT, typename YT, int DIN, int KH, bool WRITE_Y, bool WRITE_HF>
__device__ __forceinline__ void gru_scan_body(
    const XT* __restrict__ xin,
    const float* __restrict__ Wih, const float* __restrict__ Whh,
    const float* __restrict__ bih, const float* __restrict__ bhh,
    int dir, YT* __restrict__ y, float* __restrict__ hf)
{
    static_assert((KH & 1) == 0, "even KH");
    const int tid  = threadIdx.x;
    const int w    = tid >> 6;
    const int lane = tid & 63;
    const int half = lane >> 5;
    const int j    = lane & 31;
    const int jj   = j < NH ? j : NH - 1;
    const int b    = blockIdx.x * 4 + w;

    __shared__ __align__(16) float hbuf[4][32];
    if (lane < 32) hbuf[w][lane] = 0.f;
    __syncthreads();

    const int klo = half ? (DIN - KH) : 0;
    float Wxr[KH], Wxz[KH], Wxn[KH];
#pragma unroll
    for (int k = 0; k < KH; ++k) {
        const bool v = half ? true : (k < DIN - KH);
        Wxr[k] = v ? Wih[(0 * NH + jj) * DIN + klo + k] : 0.f;
        Wxz[k] = v ? Wih[(1 * NH + jj) * DIN + klo + k] : 0.f;
        Wxn[k] = v ? Wih[(2 * NH + jj) * DIN + klo + k] : 0.f;
        PIN(Wxr[k]); PIN(Wxz[k]); PIN(Wxn[k]);
    }
    const int hlo = half * 16;
    float Whr[16], Whz[16], Whn[16];
#pragma unroll
    for (int k = 0; k < 16; ++k) {
        const bool v = (hlo + k) < NH;
        Whr[k] = v ? Whh[(0 * NH + jj) * NH + hlo + k] : 0.f;
        Whz[k] = v ? Whh[(1 * NH + jj) * NH + hlo + k] : 0.f;
        Whn[k] = v ? Whh[(2 * NH + jj) * NH + hlo + k] : 0.f;
        PIN(Whr[k]); PIN(Whz[k]); PIN(Whn[k]);
    }
    float b_r = 0.f, b_z = 0.f, b_xn = 0.f, b_hn = 0.f;
    if (half == 0) {
        b_r  = bih[jj] + bhh[jj];
        b_z  = bih[NH + jj] + bhh[NH + jj];
        b_xn = bih[2 * NH + jj];
        b_hn = bhh[2 * NH + jj];
    }
    PIN(b_r); PIN(b_z); PIN(b_xn); PIN(b_hn);

    const XT* xrow = xin + (size_t)b * NT * DIN + klo
                   + (dir ? (size_t)(NT - 1) * DIN : 0);
    const ptrdiff_t xstep = dir ? -DIN : DIN;
    YT* yp = nullptr;
    ptrdiff_t ystep = 0;
    if (WRITE_Y) {
        yp = y + (size_t)b * NT * 62 + dir * NH + j
           + (dir ? (size_t)(NT - 1) * 62 : 0);
        ystep = dir ? -62 : 62;
    }

    float h_prev = 0.f;
    float xa[KH], xb[KH];
    LOADX(xa, xrow);
    const XT* xpre = xrow + xstep;

    for (int s = 0; s < NT; s += 2) {
        LOADX(xb, xpre);
        if (s + 2 < NT) xpre += xstep;
        GRU_STEP(xa);
        if (WRITE_Y) yp += ystep;
        LOADX(xa, xpre);
        if (s + 3 < NT) xpre += xstep;
        GRU_STEP(xb);
        if (WRITE_Y) yp += ystep;
    }
    if (WRITE_HF && half == 0 && j < NH) hf[b * NH + j] = h_prev;
}

template<typename YT>
__global__ void __launch_bounds__(256)
__attribute__((amdgpu_waves_per_eu(2, 2)))
gru_scan_l0(const float* __restrict__ x,
            const float* __restrict__ Wf, const float* __restrict__ Uf,
            const float* __restrict__ bf, const float* __restrict__ cf,
            const float* __restrict__ Wb, const float* __restrict__ Ub,
            const float* __restrict__ bb, const float* __restrict__ cb,
            YT* __restrict__ y)
{
    const int d = blockIdx.y;
    gru_scan_body<float, YT, 36, 18, true, false>(
        x, d ? Wb : Wf, d ? Ub : Uf, d ? bb : bf, d ? cb : cf, d, y, nullptr);
}

template<typename YT>
__global__ void __launch_bounds__(256)
__attribute__((amdgpu_waves_per_eu(1, 1)))
gru_scan_l1(const YT* __restrict__ y0,
            const float* __restrict__ W, const float* __restrict__ U,
            const float* __restrict__ bi, const float* __restrict__ bh,
            float* __restrict__ hf)
{
    gru_scan_body<YT, YT, 62, 32, false, true>(y0, W, U, bi, bh, 0, (YT*)nullptr, hf);
}

template<typename YT>
__global__ void __launch_bounds__(64, 4) gru_final_t(
    const YT* __restrict__ y0, const float* __restrict__ hf,
    const float* __restrict__ Wih1b, const float* __restrict__ bih1b,
    const float* __restrict__ bhh1b,
    const float* __restrict__ fcw, const float* __restrict__ fcb,
    float* __restrict__ out)
{
    const int b = blockIdx.x;
    const int lane = threadIdx.x;
    __shared__ float row[62];
    __shared__ float xg[NG];
    __shared__ float last[62];
    const YT* yl = y0 + ((size_t)b * NT + (NT - 1)) * 62;
    if (lane < 62) row[lane] = tf_(yl[lane]);
    __syncthreads();
    for (int g = lane; g < NG; g += 64) {
        float a = bih1b[g];
        const float* wr = Wih1b + g * 62;
#pragma unroll
        for (int k = 0; k < 62; ++k) a = fmaf(wr[k], row[k], a);
        xg[g] = a;
    }
    if (lane < NH) last[lane] = hf[b * NH + lane];
    __syncthreads();
    if (lane < NH) {
        const float r = sig_(xg[lane] + bhh1b[lane]);
        const float z = sig_(xg[NH + lane] + bhh1b[NH + lane]);
        const float n = th_(xg[2 * NH + lane] + r * bhh1b[2 * NH + lane]);
        last[NH + lane] = (1.f - z) * n;
    }
    __syncthreads();
    if (lane < NC) {
        float a = fcb[lane];
        const float* wr = fcw + lane * 62;
#pragma unroll
        for (int k = 0; k < 62; ++k) a = fmaf(wr[k], last[k], a);
        out[b * NC + lane] = a;
    }
}

// ============================== launcher ====================================

extern "C" void kernel_launch(void* const* d_in, const int* in_sizes, int n_in,
                              void* d_out, int out_size, void* d_ws, size_t ws_size,
                              hipStream_t stream)
{
    const float* x     = (const float*)d_in[0];
    const float* Wih0f = (const float*)d_in[1];
    const float* Whh0f = (const float*)d_in[2];
    const float* bih0f = (const float*)d_in[3];
    const float* bhh0f = (const float*)d_in[4];
    const float* Wih0b = (const float*)d_in[5];
    const float* Whh0b = (const float*)d_in[6];
    const float* bih0b = (const float*)d_in[7];
    const float* bhh0b = (const float*)d_in[8];
    const float* Wih1f = (const float*)d_in[9];
    const float* Whh1f = (const float*)d_in[10];
    const float* bih1f = (const float*)d_in[11];
    const float* bhh1f = (const float*)d_in[12];
    const float* Wih1b = (const float*)d_in[13];
    const float* Whh1b = (const float*)d_in[14];  // unused: single step from h0=0
    const float* bih1b = (const float*)d_in[15];
    const float* bhh1b = (const float*)d_in[16];
    const float* fcw   = (const float*)d_in[17];
    const float* fcb   = (const float*)d_in[18];
    float* out = (float*)d_out;
    (void)Whh1b; (void)in_sizes; (void)n_in; (void)out_size;

    const size_t y0_bytes = (size_t)BT * 62 * 4;
    const size_t hf_bytes = (size_t)NB * NH * 4;
    const size_t xg_bytes = (size_t)2 * BT * XGP * 4;
    const size_t need_A   = y0_bytes + 256 + hf_bytes + 256 + xg_bytes + 256;

    const size_t y0_elems  = (size_t)BT * 62;
    const size_t need_f32  = y0_elems * 4 + 256 + hf_bytes;
    const size_t need_bf16 = y0_elems * 2 + 256 + hf_bytes;

    const dim3 blk(256);
    if (ws_size >= need_A) {
        char* p = (char*)d_ws;
        float* y0 = (float*)p;                 p += (y0_bytes + 255) & ~(size_t)255;
        float* hf = (float*)p;                 p += (hf_bytes + 255) & ~(size_t)255;
        float* xg = (float*)p;

        // layer 0: xg for both dirs, then lean scans
        gru_xg<36, 2><<<dim3(BT / 256), blk, 0, stream>>>(
            x, Wih0f, bih0f, Wih0b, bih0b, xg);
        gru_scan_lean_l0<<<dim3(NB / 4, 2), blk, 0, stream>>>(
            xg, Whh0f, bhh0f, Whh0b, bhh0b, y0);
        // layer 1 forward: xg from y0 (reuse xg buffer), lean scan
        gru_xg<62, 1><<<dim3(BT / 256), blk, 0, stream>>>(
            y0, Wih1f, bih1f, nullptr, nullptr, xg);
        gru_scan_lean_l1<<<dim3(NB / 4), blk, 0, stream>>>(
            xg, Whh1f, bhh1f, hf);
        gru_final<<<dim3(NB), dim3(64), 0, stream>>>(
            y0, hf, Wih1b, bih1b, bhh1b, fcw, fcb, out);
    } else if (ws_size >= need_f32) {
        float* y0 = (float*)d_ws;
        float* hf = (float*)((char*)d_ws + ((y0_elems * 4 + 255) & ~(size_t)255));
        gru_scan_l0<float><<<dim3(NB / 4, 2), blk, 0, stream>>>(
            x, Wih0f, Whh0f, bih0f, bhh0f, Wih0b, Whh0b, bih0b, bhh0b, y0);
        gru_scan_l1<float><<<dim3(NB / 4, 1), blk, 0, stream>>>(
            y0, Wih1f, Whh1f, bih1f, bhh1f, hf);
        gru_final_t<float><<<dim3(NB), dim3(64), 0, stream>>>(
            y0, hf, Wih1b, bih1b, bhh1b, fcw, fcb, out);
    } else if (ws_size >= need_bf16) {
        __hip_bfloat16* y0 = (__hip_bfloat16*)d_ws;
        float* hf = (float*)((char*)d_ws + ((y0_elems * 2 + 255) & ~(size_t)255));
        gru_scan_l0<__hip_bfloat16><<<dim3(NB / 4, 2), blk, 0, stream>>>(
            x, Wih0f, Whh0f, bih0f, bhh0f, Wih0b, Whh0b, bih0b, bhh0b, y0);
        gru_scan_l1<__hip_bfloat16><<<dim3(NB / 4, 1), blk, 0, stream>>>(
            y0, Wih1f, Whh1f, bih1f, bhh1f, hf);
        gru_final_t<__hip_bfloat16><<<dim3(NB), dim3(64), 0, stream>>>(
            y0, hf, Wih1b, bih1b, bhh1b, fcw, fcb, out);
    }
}

// Round 11
// 563.620 us; speedup vs baseline: 1.0133x; 1.0120x over previous
//
#include <hip/hip_runtime.h>

// ---------------------------------------------------------------------------
// 2-layer bidirectional GRU, B=1024 T=512 H=31 IN=36 -> last step -> FC(62->7)
//
// Round 11: back to the PROVEN r2 structure (passed 3x, absmax 2.4e-7), with
// one mechanical, numerics-identical change: weights staged in LDS per block
// (per-lane-packed, stride = 4 mod 8 dwords -> conflict-free ds_read_b128),
// read per step instead of the compiler's re-materialized per-step GLOBAL
// loads (the measured ~3.3x VALU bloat: 356 vs ~110 instr/step).
//  * FMA accumulation order per accumulator preserved exactly; Wx slices
//    zero-padded to WXP -> padded FMAs add exact 0. Output bit-identical.
//  * y0 stays f32 (ws need = 130.15 MB, proven present by rounds 2-5).
//  * l0: DIN=36, KH=18/half, WXP=20, WSTR=108 (27.6 KB LDS/block).
//  * l1: DIN=62, KH=32/half, WXP=32, WSTR=148 (37.9 KB LDS/block).
//  * L1 backward = ONE GRU step at t=T-1 (h0=0) in gru_final.
// ---------------------------------------------------------------------------

#define NB 1024
#define NT 512
#define NH 31
#define NG 93
#define NC 7
#define BT (NB * NT)

__device__ __forceinline__ float sig_(float x) { return 1.f / (1.f + __expf(-x)); }
__device__ __forceinline__ float th_(float x)  { float e = __expf(2.f * x); return (e - 1.f) / (e + 1.f); }

// One GRU step. Uses enclosing scope: wl, hbuf, w, hlo, b_*, h_prev, yp,
// ystep, half, j, WXP (template const). Weight reads are ds_read_b128.
#define STEPB(XV)                                                         \
    do {                                                                  \
        const float4 g0 = *(const float4*)&hbuf[w][hlo + 0];              \
        const float4 g1 = *(const float4*)&hbuf[w][hlo + 4];              \
        const float4 g2 = *(const float4*)&hbuf[w][hlo + 8];              \
        const float4 g3 = *(const float4*)&hbuf[w][hlo + 12];             \
        float hv[16];                                                     \
        hv[0]=g0.x;  hv[1]=g0.y;  hv[2]=g0.z;  hv[3]=g0.w;                \
        hv[4]=g1.x;  hv[5]=g1.y;  hv[6]=g1.z;  hv[7]=g1.w;                \
        hv[8]=g2.x;  hv[9]=g2.y;  hv[10]=g2.z; hv[11]=g2.w;               \
        hv[12]=g3.x; hv[13]=g3.y; hv[14]=g3.z; hv[15]=g3.w;               \
        float ar = b_r, az = b_z, an = b_xn, ah = b_hn;                   \
        _Pragma("unroll") for (int q = 0; q < WXP / 4; ++q) {             \
            const float4 wr = *(const float4*)(wl + 0 * WXP + q * 4);     \
            const float4 wz = *(const float4*)(wl + 1 * WXP + q * 4);     \
            const float4 wn = *(const float4*)(wl + 2 * WXP + q * 4);     \
            ar = fmaf(wr.x, XV[q*4+0], ar);                               \
            ar = fmaf(wr.y, XV[q*4+1], ar);                               \
            ar = fmaf(wr.z, XV[q*4+2], ar);                               \
            ar = fmaf(wr.w, XV[q*4+3], ar);                               \
            az = fmaf(wz.x, XV[q*4+0], az);                               \
            az = fmaf(wz.y, XV[q*4+1], az);                               \
            az = fmaf(wz.z, XV[q*4+2], az);                               \
            az = fmaf(wz.w, XV[q*4+3], az);                               \
            an = fmaf(wn.x, XV[q*4+0], an);                               \
            an = fmaf(wn.y, XV[q*4+1], an);                               \
            an = fmaf(wn.z, XV[q*4+2], an);                               \
            an = fmaf(wn.w, XV[q*4+3], an);                               \
        }                                                                 \
        _Pragma("unroll") for (int q = 0; q < 4; ++q) {                   \
            const float4 ur = *(const float4*)(wl + 3 * WXP +      q * 4);\
            const float4 uz = *(const float4*)(wl + 3 * WXP + 16 + q * 4);\
            const float4 un = *(const float4*)(wl + 3 * WXP + 32 + q * 4);\
            ar = fmaf(ur.x, hv[q*4+0], ar);                               \
            ar = fmaf(ur.y, hv[q*4+1], ar);                               \
            ar = fmaf(ur.z, hv[q*4+2], ar);                               \
            ar = fmaf(ur.w, hv[q*4+3], ar);                               \
            az = fmaf(uz.x, hv[q*4+0], az);                               \
            az = fmaf(uz.y, hv[q*4+1], az);                               \
            az = fmaf(uz.z, hv[q*4+2], az);                               \
            az = fmaf(uz.w, hv[q*4+3], az);                               \
            ah = fmaf(un.x, hv[q*4+0], ah);                               \
            ah = fmaf(un.y, hv[q*4+1], ah);                               \
            ah = fmaf(un.z, hv[q*4+2], ah);                               \
            ah = fmaf(un.w, hv[q*4+3], ah);                               \
        }                                                                 \
        ar += __shfl_xor(ar, 32, 64);                                     \
        az += __shfl_xor(az, 32, 64);                                     \
        an += __shfl_xor(an, 32, 64);                                     \
        ah += __shfl_xor(ah, 32, 64);                                     \
        const float r_ = sig_(ar);                                        \
        const float z_ = sig_(az);                                        \
        const float n_ = th_(an + r_ * ah);                               \
        h_prev = n_ + z_ * (h_prev - n_);                                 \
        if (half == 0 && j < NH) {                                        \
            hbuf[w][j] = h_prev;                                          \
            if (WRITE_Y) *yp = h_prev;                                    \
        }                                                                 \
        if (WRITE_Y) yp += ystep;                                         \
    } while (0)

// LDS weight layout per lane (stride WSTR dwords, WSTR = 4 mod 8):
//   [0..WXP)        Wxr slice (klo..klo+KH, zero-padded to WXP)
//   [WXP..2WXP)     Wxz
//   [2WXP..3WXP)    Wxn
//   [3WXP+ 0..16)   Whr slice (hlo..hlo+16, zero-padded past NH)
//   [3WXP+16..32)   Whz
//   [3WXP+32..48)   Whn
template<int DIN, int KH, int WXP, int WSTR, bool WRITE_Y, bool WRITE_HF>
__device__ __forceinline__ void lds_scan(
    const float* __restrict__ xin,
    const float* __restrict__ Wih, const float* __restrict__ Whh,
    const float* __restrict__ bih, const float* __restrict__ bhh,
    int dir, float* __restrict__ y, float* __restrict__ hf)
{
    static_assert((KH & 1) == 0 && (WXP & 3) == 0 && (WSTR & 7) == 4, "layout");
    const int tid  = threadIdx.x;
    const int w    = tid >> 6;
    const int lane = tid & 63;
    const int half = lane >> 5;
    const int j    = lane & 31;
    const int jj   = j < NH ? j : NH - 1;
    const int b    = blockIdx.x * 4 + w;

    __shared__ __align__(16) float hbuf[4][32];
    __shared__ __align__(16) float wlds[64][WSTR];

    const int klo = half ? (DIN - KH) : 0;
    const int hlo = half * 16;

    // one-time staging: wave g in {0,1,2} fills gate g for every lane value
    if (w < 3) {
        const int g = w;
        for (int k = 0; k < WXP; ++k) {
            const bool v = (k < KH) && (half ? true : (k < DIN - KH));
            wlds[lane][g * WXP + k] = v ? Wih[(g * NH + jj) * DIN + klo + k] : 0.f;
        }
        for (int k = 0; k < 16; ++k) {
            const bool v = (hlo + k) < NH;
            wlds[lane][3 * WXP + g * 16 + k] = v ? Whh[(g * NH + jj) * NH + hlo + k] : 0.f;
        }
    }
    if (lane < 32) hbuf[w][lane] = 0.f;

    float b_r = 0.f, b_z = 0.f, b_xn = 0.f, b_hn = 0.f;
    if (half == 0) {
        b_r  = bih[jj] + bhh[jj];
        b_z  = bih[NH + jj] + bhh[NH + jj];
        b_xn = bih[2 * NH + jj];
        b_hn = bhh[2 * NH + jj];
    }
    __syncthreads();

    const float* wl = &wlds[lane][0];

    const float* xrow = xin + (size_t)b * NT * DIN + klo
                      + (dir ? (size_t)(NT - 1) * DIN : 0);
    const ptrdiff_t xstep = dir ? -DIN : DIN;
    float* yp = nullptr;
    ptrdiff_t ystep = 0;
    if (WRITE_Y) {
        yp = y + (size_t)b * NT * 62 + dir * NH + j
           + (dir ? (size_t)(NT - 1) * 62 : 0);
        ystep = dir ? -62 : 62;
    }

    float h_prev = 0.f;
    float xa[WXP], xb[WXP];
#pragma unroll
    for (int k = 0; k < WXP; ++k) { xa[k] = 0.f; xb[k] = 0.f; }
#pragma unroll
    for (int k = 0; k < KH; k += 2) {
        float2 v = *(const float2*)(xrow + k); xa[k] = v.x; xa[k + 1] = v.y;
    }
    const float* xpre = xrow + xstep;

    for (int s = 0; s < NT; s += 2) {
#pragma unroll
        for (int k = 0; k < KH; k += 2) {
            float2 v = *(const float2*)(xpre + k); xb[k] = v.x; xb[k + 1] = v.y;
        }
        if (s + 2 < NT) xpre += xstep;
        STEPB(xa);
#pragma unroll
        for (int k = 0; k < KH; k += 2) {
            float2 v = *(const float2*)(xpre + k); xa[k] = v.x; xa[k + 1] = v.y;
        }
        if (s + 3 < NT) xpre += xstep;
        STEPB(xb);
    }
    if (WRITE_HF && half == 0 && j < NH) hf[(size_t)b * NH + j] = h_prev;
}

__global__ void __launch_bounds__(256)
__attribute__((amdgpu_waves_per_eu(2, 2)))
gru_scan_l0(const float* __restrict__ x,
            const float* __restrict__ Wf, const float* __restrict__ Uf,
            const float* __restrict__ bf, const float* __restrict__ cf,
            const float* __restrict__ Wb, const float* __restrict__ Ub,
            const float* __restrict__ bb, const float* __restrict__ cb,
            float* __restrict__ y)
{
    const int d = blockIdx.y;
    lds_scan<36, 18, 20, 108, true, false>(
        x, d ? Wb : Wf, d ? Ub : Uf, d ? bb : bf, d ? cb : cf, d, y, nullptr);
}

__global__ void __launch_bounds__(256)
__attribute__((amdgpu_waves_per_eu(1, 1)))
gru_scan_l1(const float* __restrict__ y0,
            const float* __restrict__ W, const float* __restrict__ U,
            const float* __restrict__ bi, const float* __restrict__ bh,
            float* __restrict__ hf)
{
    lds_scan<62, 32, 32, 148, false, true>(y0, W, U, bi, bh, 0, nullptr, hf);
}

// ============== final: l1-bwd single step at t=NT-1 (h0=0) + FC ============
__global__ void __launch_bounds__(64, 4) gru_final(
    const float* __restrict__ y0, const float* __restrict__ hf,
    const float* __restrict__ Wih1b, const float* __restrict__ bih1b,
    const float* __restrict__ bhh1b,
    const float* __restrict__ fcw, const float* __restrict__ fcb,
    float* __restrict__ out)
{
    const int b = blockIdx.x;
    const int lane = threadIdx.x;
    __shared__ float row[62];
    __shared__ float xgs[NG];
    __shared__ float last[62];
    const float* yl = y0 + ((size_t)b * NT + (NT - 1)) * 62;
    if (lane < 62) row[lane] = yl[lane];
    __syncthreads();
    for (int g = lane; g < NG; g += 64) {
        float a = bih1b[g];
        const float* wr = Wih1b + g * 62;
#pragma unroll
        for (int k = 0; k < 62; ++k) a = fmaf(wr[k], row[k], a);
        xgs[g] = a;
    }
    if (lane < NH) last[lane] = hf[(size_t)b * NH + lane];
    __syncthreads();
    if (lane < NH) {
        const float r = sig_(xgs[lane] + bhh1b[lane]);
        const float z = sig_(xgs[NH + lane] + bhh1b[NH + lane]);
        const float n = th_(xgs[2 * NH + lane] + r * bhh1b[2 * NH + lane]);
        last[NH + lane] = (1.f - z) * n;   // + z*h0, h0 = 0
    }
    __syncthreads();
    if (lane < NC) {
        float a = fcb[lane];
        const float* wr = fcw + lane * 62;
#pragma unroll
        for (int k = 0; k < 62; ++k) a = fmaf(wr[k], last[k], a);
        out[b * NC + lane] = a;
    }
}

// ============================== launcher ====================================

extern "C" void kernel_launch(void* const* d_in, const int* in_sizes, int n_in,
                              void* d_out, int out_size, void* d_ws, size_t ws_size,
                              hipStream_t stream)
{
    const float* x     = (const float*)d_in[0];
    const float* Wih0f = (const float*)d_in[1];
    const float* Whh0f = (const float*)d_in[2];
    const float* bih0f = (const float*)d_in[3];
    const float* bhh0f = (const float*)d_in[4];
    const float* Wih0b = (const float*)d_in[5];
    const float* Whh0b = (const float*)d_in[6];
    const float* bih0b = (const float*)d_in[7];
    const float* bhh0b = (const float*)d_in[8];
    const float* Wih1f = (const float*)d_in[9];
    const float* Whh1f = (const float*)d_in[10];
    const float* bih1f = (const float*)d_in[11];
    const float* bhh1f = (const float*)d_in[12];
    const float* Wih1b = (const float*)d_in[13];
    const float* Whh1b = (const float*)d_in[14];  // unused: single step from h0=0
    const float* bih1b = (const float*)d_in[15];
    const float* bhh1b = (const float*)d_in[16];
    const float* fcw   = (const float*)d_in[17];
    const float* fcb   = (const float*)d_in[18];
    float* out = (float*)d_out;
    (void)Whh1b; (void)in_sizes; (void)n_in; (void)out_size; (void)ws_size;

    // proven layout (rounds 2-5 ran this): y0 f32 130.0 MB | hf 127 KB
    const size_t y0_elems = (size_t)BT * 62;
    float* y0 = (float*)d_ws;
    float* hf = (float*)((char*)d_ws + ((y0_elems * 4 + 255) & ~(size_t)255));

    const dim3 blk(256);
    gru_scan_l0<<<dim3(NB / 4, 2), blk, 0, stream>>>(
        x, Wih0f, Whh0f, bih0f, bhh0f, Wih0b, Whh0b, bih0b, bhh0b, y0);
    gru_scan_l1<<<dim3(NB / 4, 1), blk, 0, stream>>>(
        y0, Wih1f, Whh1f, bih1f, bhh1f, hf);
    gru_final<<<dim3(NB), dim3(64), 0, stream>>>(
        y0, hf, Wih1b, bih1b, bhh1b, fcw, fcb, out);
}